// Round 4
// baseline (229.907 us; speedup 1.0000x reference)
//
#include <hip/hip_runtime.h>
#include <hip/hip_bf16.h>
#include <stdint.h>

// ---------------------------------------------------------------------------
// SplitCausalSelfAttention on MI355X (gfx950), bf16 MFMA implementation.
// B=4, T=2048, C=1024, H=16, D=64.
// R15: frag-ahead register double-buffering in both GEMM cores.  R14's cycle
//      ledger: K-tile = 5030 cyc vs MFMA 1548 + LDS-read 1930 — the 2-barrier
//      phase serializes read-drain and MFMA.  Now each phase issues the NEXT
//      phase's ds_reads inside its own MFMA region (after the leading
//      barrier), into alternate xf/wf register buffers (unrolled x2 so all
//      indices compile-time), overlapping LDS drain with MFMA.  Residency:
//      reads of tile t+1 only occur after the vmcnt(6) gate at t.p2 (ledger
//      verified, incl. 0-gate tail); WAR: every staging issue still lands a
//      full barrier-pair after its slot's (earlier) last read.
//      sched_barrier(0) pins the read block above the MFMA cluster.
//      Same trick in proj's 2-phase core (gates already every-phase).
//      attn/cast unchanged.
// ---------------------------------------------------------------------------

typedef unsigned short u16;
typedef __attribute__((ext_vector_type(8))) __bf16 bf16x8;  // 4 VGPRs (A/B frag, K=32)
typedef __attribute__((ext_vector_type(4))) float  f32x4;   // C/D frag
typedef __attribute__((ext_vector_type(4))) unsigned short u16x4;
typedef __attribute__((ext_vector_type(8))) unsigned short u16x8;
typedef __attribute__((ext_vector_type(4))) short s16x4;    // 2 VGPRs (A/B frag, K=16)

#define B_  4
#define T_  2048
#define C_  1024
#define H_  16
#define D_  64
#define BT_ (B_ * T_)
#define NT_ 16        // K-tiles of 64 over K=1024

// scale = 1/sqrt(D) folded with log2(e) so softmax uses exp2
#define Q_SCALE 0.1803368801111204f

__device__ __forceinline__ u16 f32_to_bf16(float f) {
    unsigned int u = __float_as_uint(f);
    unsigned int r = (u + 0x7FFFu + ((u >> 16) & 1u)) >> 16;
    return (u16)r;
}

__device__ __forceinline__ unsigned int pk_bf16(float a, float b) {
    float2 f2; f2.x = a; f2.y = b;
    __hip_bfloat162 h = __float22bfloat162_rn(f2);
    return *(unsigned int*)&h;
}

__device__ __forceinline__ void async16(const void* g, void* lds) {
    __builtin_amdgcn_global_load_lds(
        (const __attribute__((address_space(1))) void*)g,
        (__attribute__((address_space(3))) void*)lds, 16, 0, 0);
}

// ---------------------------------------------------------------------------
// single cast kernel: X (8192 blocks) + 4 weights (1024 blocks each)
// ---------------------------------------------------------------------------
__global__ void cast_all_kernel(const float* __restrict__ X,
                                const float* __restrict__ w0, const float* __restrict__ w1,
                                const float* __restrict__ w2, const float* __restrict__ w3,
                                u16* __restrict__ xo,
                                u16* __restrict__ o0, u16* __restrict__ o1,
                                u16* __restrict__ o2, u16* __restrict__ o3) {
    int id = blockIdx.x;
    const float* in; u16* out; int i;
    if (id < 8192) {
        in = X; out = xo; i = id * 256 + threadIdx.x;
    } else {
        int k = (id - 8192) >> 10;
        in  = (k == 0) ? w0 : (k == 1) ? w1 : (k == 2) ? w2 : w3;
        out = (k == 0) ? o0 : (k == 1) ? o1 : (k == 2) ? o2 : o3;
        i = ((id - 8192) & 1023) * 256 + threadIdx.x;
    }
    float4 v = ((const float4*)in)[i];
    u16x4 o;
    o[0] = f32_to_bf16(v.x); o[1] = f32_to_bf16(v.y);
    o[2] = f32_to_bf16(v.z); o[3] = f32_to_bf16(v.w);
    ((u16x4*)out)[i] = o;
}

// ---------------------------------------------------------------------------
// qkv 128x384 3-phase core with frag-ahead pipelining.
// LDS: dbuf d at d*65536; unit u at u*16384: u0=A(X) rows0-127,
// u1/u2/u3 = B(Wcat) rows 0-127/128-255/256-383.  k-rotation swizzle
// (slot s holds k-group (s-r)&7), measured 0-conflict.
// Phase p uses wf frags nj={2p,2p+1} (unit 1+p); xf (u0) used all phases.
// Frag-ahead: phase p issues NEXT phase's ds_reads after its leading
// barrier (p0->wf(t,1); p1->wf(t,2); p2->xf(t+1)+wf(t+1,0)), overlapping
// their drain with the MFMA cluster.  Residency: tile t+1 gated by
// vmcnt(6) at t.p2 BEFORE its leading barrier, so p2's next-tile reads
// (issued after that barrier) are safe.  Staging stream unchanged from
// R14: t.p0 -> (t+1).u3; t.p1 -> (t+2).u0,u1; t.p2 -> (t+2).u2.  WAR:
// u0/u1 last-read issued (t-1).p2, consumed t.p0, staged t.p1;
// u2 read-issued t.p0, consumed t.p1, staged t.p2; u3 read-issued t.p1,
// consumed t.p2, staged (other dbuf) t.p0.  All >=1 barrier-pair apart.
// ---------------------------------------------------------------------------
#define RD_WF(CB, P, DST)                                                        \
    _Pragma("unroll") for (int e_ = 0; e_ < 2; ++e_)                             \
      _Pragma("unroll") for (int ks_ = 0; ks_ < 2; ++ks_)                        \
        DST[e_][ks_] = *(const bf16x8*)((CB) + bwoff[2 * (P) + e_][ks_]);

#define RD_XF(CB, DST)                                                           \
    _Pragma("unroll") for (int mi_ = 0; mi_ < 4; ++mi_)                          \
      _Pragma("unroll") for (int ks_ = 0; ks_ < 2; ++ks_)                        \
        DST[mi_][ks_] = *(const bf16x8*)((CB) + axoff[mi_][ks_]);

// one phase: staging issue -> [gate] -> barrier -> next-phase ds_reads ->
// sched pin -> setprio -> 16 MFMA (current frags) -> setprio -> barrier
#define PH3(ISSUE, GATE, XF, WF, PIDX, ...)                                      \
  {                                                                              \
    ISSUE;                                                                       \
    if ((GATE) == 6)      asm volatile("s_waitcnt vmcnt(6)" ::: "memory");       \
    else if ((GATE) == 0) asm volatile("s_waitcnt vmcnt(0)" ::: "memory");       \
    __builtin_amdgcn_s_barrier();                                                \
    asm volatile("" ::: "memory");                                               \
    __VA_ARGS__;                                                                 \
    __builtin_amdgcn_sched_barrier(0);                                           \
    __builtin_amdgcn_s_setprio(1);                                               \
    _Pragma("unroll") for (int mi = 0; mi < 4; ++mi)                             \
      _Pragma("unroll") for (int e = 0; e < 2; ++e) {                            \
        f32x4 a_ = acc[mi][2 * (PIDX) + e];                                      \
        if (SWAPV) {                                                             \
          a_ = __builtin_amdgcn_mfma_f32_16x16x32_bf16(XF[mi][0], WF[e][0], a_, 0, 0, 0); \
          a_ = __builtin_amdgcn_mfma_f32_16x16x32_bf16(XF[mi][1], WF[e][1], a_, 0, 0, 0); \
        } else {                                                                 \
          a_ = __builtin_amdgcn_mfma_f32_16x16x32_bf16(WF[e][0], XF[mi][0], a_, 0, 0, 0); \
          a_ = __builtin_amdgcn_mfma_f32_16x16x32_bf16(WF[e][1], XF[mi][1], a_, 0, 0, 0); \
        }                                                                        \
        acc[mi][2 * (PIDX) + e] = a_;                                            \
      }                                                                          \
    __builtin_amdgcn_s_setprio(0);                                               \
    asm volatile("" ::: "memory");                                               \
    __builtin_amdgcn_s_barrier();                                                \
    asm volatile("" ::: "memory");                                               \
  }

// one K-tile: CB = this tile's dbuf, CBN = next tile's dbuf.
// XFC used all 3 phases; p2 reads XFN/WF1 for tile T+1 (if RDN).
#define TILE3(T, CB, CBN, XFC, XFN, WF0, WF1, GU3, GNX, GATE_P2, RDN)            \
  PH3({ if (GU3) issue_unit((T) + 1, 3); }, -1, XFC, WF0, 0,                     \
      { RD_WF(CB, 1, WF1); });                                                   \
  PH3({ if (GNX) { issue_unit((T) + 2, 0); issue_unit((T) + 2, 1); } }, -1,      \
      XFC, WF1, 1, { RD_WF(CB, 2, WF0); });                                      \
  PH3({ if (GNX) issue_unit((T) + 2, 2); }, GATE_P2, XFC, WF0, 2,                \
      { if (RDN) { RD_XF(CBN, XFN); RD_WF(CBN, 0, WF1); } });

template<bool SWAPV>
__device__ __forceinline__ void qkv384_core(const u16* __restrict__ Arow,
                                            const u16* __restrict__ Brow,
                                            char* lds, f32x4 (&acc)[4][6])
{
    int tid = threadIdx.x, lane = tid & 63, w = tid >> 6;
    int quad = lane >> 4, l15 = lane & 15;
    int wm = w >> 2, wn = w & 3;

    // staging: 2 async16/thread/unit; pre-swizzled global k-group
    int gc = (((tid & 7) - (tid >> 3)) & 7) * 8;
    const u16* asrc = Arow + (size_t)(tid >> 3) * C_ + gc;
    const u16* bsrc = Brow + (size_t)(tid >> 3) * C_ + gc;

    auto issue_unit = [&](int kt, int u) {
        char* d = lds + ((kt & 1) << 16) + (u << 14) + (w << 10);
        int ko = kt * 64;
        const u16* s = (u == 0) ? (asrc + ko)
                                : (bsrc + (size_t)(u - 1) * 128 * C_ + ko);
        async16(s, d);
        async16(s + (size_t)64 * C_, d + 8192);
    };

    // loop-invariant LDS read byte offsets
    int axoff[4][2], bwoff[6][2];
#pragma unroll
    for (int mi = 0; mi < 4; ++mi) {
        int r = wm * 64 + mi * 16 + l15;
#pragma unroll
        for (int ks = 0; ks < 2; ++ks)
            axoff[mi][ks] = r * 128 + (((ks * 4 + quad + r) & 7) << 4);
    }
#pragma unroll
    for (int nj = 0; nj < 6; ++nj) {
        int r = wn * 32 + (nj & 1) * 16 + l15;
#pragma unroll
        for (int ks = 0; ks < 2; ++ks)
            bwoff[nj][ks] = (1 + (nj >> 1)) * 16384 + r * 128 + (((ks * 4 + quad + r) & 7) << 4);
    }

    bf16x8 xfA[4][2], xfB[4][2];     // A-frag double buffer (per K-tile)
    bf16x8 wfA[2][2], wfB[2][2];     // B-frag double buffer (per phase)

    char* db0 = lds;
    char* db1 = lds + 65536;

    // prologue: t0 all units + t1.{u0,u1,u2}; gate t0 (6 younger = t1's);
    // then pre-read tile0 p0 frags (xfA, wfA).
    issue_unit(0, 0); issue_unit(0, 1); issue_unit(0, 2); issue_unit(0, 3);
    issue_unit(1, 0); issue_unit(1, 1); issue_unit(1, 2);
    asm volatile("s_waitcnt vmcnt(6)" ::: "memory");
    __builtin_amdgcn_s_barrier();
    asm volatile("" ::: "memory");
    RD_XF(db0, xfA);
    RD_WF(db0, 0, wfA);

    // main pairs: tiles 0..13 (all staging live, gate 6, always read next)
    for (int t = 0; t < NT_ - 2; t += 2) {
        TILE3(t,     db0, db1, xfA, xfB, wfA, wfB, 1, 1, 6, 1);
        TILE3(t + 1, db1, db0, xfB, xfA, wfB, wfA, 1, 1, 6, 1);
    }
    // peeled tail: tile 14 (stage u3(15) only; gate 0 drains; read tile15
    // frags) and tile 15 (no staging, no gates, no next-read).
    TILE3(NT_ - 2, db0, db1, xfA, xfB, wfA, wfB, 1, 0, 0, 1);
    TILE3(NT_ - 1, db1, db0, xfB, xfA, wfB, wfA, 0, 0, -1, 0);
}

// ---------------------------------------------------------------------------
// Fused QKV: C[8192,3072] = X . Wcat^T, 128x384 tiles, grid 512 (2 exact
// rounds).  wg = (id&7)*64 + (id>>3); bn = wg>>6 (= XCD, W panel L2-pinned),
// bm = wg&63.  Wcat = contiguous [3072,1024] (Wq|Wk|Wv adjacent in ws).
// ---------------------------------------------------------------------------
__global__ __launch_bounds__(512, 2) void qkv_gemm384(
    const u16* __restrict__ Xb, const u16* __restrict__ Wcat,
    u16* __restrict__ Qb, u16* __restrict__ Kb, u16* __restrict__ Vtb)
{
    __shared__ __attribute__((aligned(128))) char LDSRAW[131072];

    int id = blockIdx.x;
    int wg = (id & 7) * 64 + (id >> 3);      // bijective XCD swizzle (512=8*64)
    int bn = wg >> 6;                        // 0..7 (uniform per XCD)
    int bm = wg & 63;                        // 0..63
    int m0 = bm * 128;
    int chb = bn * 384;

    const u16* Arow = Xb   + (size_t)m0  * C_;
    const u16* Brow = Wcat + (size_t)chb * C_;

    f32x4 acc[4][6];
    const f32x4 z4 = {0.f, 0.f, 0.f, 0.f};
#pragma unroll
    for (int i = 0; i < 4; ++i)
#pragma unroll
        for (int j = 0; j < 6; ++j) acc[i][j] = z4;

    int tid = threadIdx.x, lane = tid & 63, w = tid >> 6;
    int quad = lane >> 4, l15 = lane & 15;
    int wm = w >> 2, wn = w & 3;

    if (bn < 6) {
        // Q/K (and bn5's V spill-over).  D row = ch (quad*4+rr), col = t (l15).
        qkv384_core<false>(Arow, Brow, LDSRAW, acc);
#pragma unroll
        for (int mi = 0; mi < 4; ++mi) {
            int tg = m0 + wm * 64 + mi * 16 + l15;
#pragma unroll
            for (int nj = 0; nj < 6; ++nj) {
                int colb = chb + (nj >> 1) * 128 + wn * 32 + (nj & 1) * 16 + quad * 4;
                if (colb < 2048) {
                    u16* OUT = (colb < 1024) ? Qb : Kb;
                    float sc = (colb < 1024) ? Q_SCALE : 1.0f;
                    u16x4 v;
#pragma unroll
                    for (int rr = 0; rr < 4; ++rr) v[rr] = f32_to_bf16(acc[mi][nj][rr] * sc);
                    *(u16x4*)&OUT[(size_t)tg * C_ + (colb & 1023)] = v;
                } else {
                    // V frags of the K|V boundary block: scalar stores,
                    // 16-lane t-runs (32B coalesced groups) along T.
                    int b_ = tg >> 11, tl = tg & (T_ - 1);
#pragma unroll
                    for (int rr = 0; rr < 4; ++rr) {
                        int ch = colb + rr;
                        int h = (ch >> 6) & 15, d = ch & 63;
                        Vtb[((size_t)(b_ * H_ + h) * D_ + d) * T_ + tl] =
                            f32_to_bf16(acc[mi][nj][rr]);
                    }
                }
            }
        }
    } else {
        // pure-V blocks: swapped operands.  D row = t (quad*4+rr), col = ch (l15).
        qkv384_core<true>(Arow, Brow, LDSRAW, acc);
#pragma unroll
        for (int mi = 0; mi < 4; ++mi) {
            int t0 = m0 + wm * 64 + mi * 16 + quad * 4;
            int b_ = t0 >> 11, tl = t0 & (T_ - 1);
#pragma unroll
            for (int nj = 0; nj < 6; ++nj) {
                int ch = chb + (nj >> 1) * 128 + wn * 32 + (nj & 1) * 16 + l15;
                int h = (ch >> 6) & 15, d = ch & 63;
                u16x4 v;
#pragma unroll
                for (int rr = 0; rr < 4; ++rr) v[rr] = f32_to_bf16(acc[mi][nj][rr]);
                *(u16x4*)&Vtb[((size_t)(b_ * H_ + h) * D_ + d) * T_ + tl] = v;
            }
        }
    }
}

// ---------------------------------------------------------------------------
// proj 2-phase pipelined core with frag-ahead (phase p issues phase p+1's
// 8 ds_reads inside its MFMA region).  Residency: every-phase vmcnt(6)
// gates already prove one-phase-early reads resident (tail 6/3/0 ledger
// verified).  Frag buffers alternate per phase (2 phases/tile -> stable
// A/B naming, all indices compile-time).
// ---------------------------------------------------------------------------
#define RD8(CB, KS, FX, FW)                                                      \
    _Pragma("unroll") for (int i_ = 0; i_ < 4; ++i_) {                           \
        FX[i_] = *(const bf16x8*)((CB) + (KS) * 8192  + xoff[i_]);               \
        FW[i_] = *(const bf16x8*)((CB) + (KS) * 16384 + woff[i_]);               \
    }

#define PPH(ISSUE, GATE, FX, FW, ...)                                            \
  {                                                                              \
    ISSUE;                                                                       \
    if ((GATE) == 6)      asm volatile("s_waitcnt vmcnt(6)" ::: "memory");       \
    else if ((GATE) == 3) asm volatile("s_waitcnt vmcnt(3)" ::: "memory");       \
    else if ((GATE) == 0) asm volatile("s_waitcnt vmcnt(0)" ::: "memory");       \
    __builtin_amdgcn_s_barrier();                                                \
    asm volatile("" ::: "memory");                                               \
    __VA_ARGS__;                                                                 \
    __builtin_amdgcn_sched_barrier(0);                                           \
    __builtin_amdgcn_s_setprio(1);                                               \
    _Pragma("unroll") for (int i = 0; i < 4; ++i)                                \
      _Pragma("unroll") for (int j = 0; j < 4; ++j)                              \
        acc[i][j] = __builtin_amdgcn_mfma_f32_16x16x32_bf16(FW[j], FX[i], acc[i][j], 0, 0, 0); \
    __builtin_amdgcn_s_setprio(0);                                               \
    asm volatile("" ::: "memory");                                               \
    __builtin_amdgcn_s_barrier();                                                \
    asm volatile("" ::: "memory");                                               \
  }

__device__ __forceinline__ void gemm8p_core(const u16* __restrict__ Arow,
                                            const u16* __restrict__ Brow,
                                            char* lds, f32x4 (&acc)[4][4])
{
    int tid  = threadIdx.x;
    int lane = tid & 63, w = tid >> 6;
    int quad = lane >> 4, l15 = lane & 15;
    int wm = w >> 2, wn = w & 3;

    int r  = tid >> 2, s4 = tid & 3;
    int kg = ((s4 - (r >> 1)) & 3) * 8;
    const u16* xsrc  = Arow + (size_t)r * C_ + kg;
    const u16* wsrc0 = Brow + (size_t)r * C_ + kg;
    const u16* wsrc1 = Brow + (size_t)(128 + r) * C_ + kg;
    int wu = w << 10;

    int xoff[4], woff[4];
#pragma unroll
    for (int i = 0; i < 4; ++i) {
        int rx = wm * 64 + i * 16 + l15;
        xoff[i] = rx * 64 + (((rx >> 1) + quad) & 3) * 16;
        int rw = wn * 64 + i * 16 + l15;
        woff[i] = 16384 + rw * 64 + (((rw >> 1) + quad) & 3) * 16;
    }

    auto issue_group = [&](int g) {
        int db = (g >> 1) & 1, ks = g & 1;
        int koff = (g >> 1) * 64 + ks * 32;
        char* ldb = lds + db * 49152;
        async16(xsrc  + koff, ldb + ks * 8192 + wu);
        async16(wsrc0 + koff, ldb + 16384 + ks * 16384 + wu);
        async16(wsrc1 + koff, ldb + 16384 + ks * 16384 + 8192 + wu);
    };

    bf16x8 fAx[4], fAw[4], fBx[4], fBw[4];

    issue_group(0); issue_group(1); issue_group(2);
    asm volatile("s_waitcnt vmcnt(6)" ::: "memory");
    __builtin_amdgcn_s_barrier();
    asm volatile("" ::: "memory");
    RD8(lds, 0, fAx, fAw);            // (0, ks0): complete after vmcnt(6)

    for (int t = 0; t < NT_ - 1; ++t) {
        char* cb  = lds + (t & 1) * 49152;
        char* cbn = lds + ((t + 1) & 1) * 49152;
        // p0: use A, read (t, ks1) -> B.  gate 6 (all t<=14).
        PPH({ issue_group(2 * t + 3); }, 6, fAx, fAw, { RD8(cb, 1, fBx, fBw); });
        // p1: use B, read (t+1, ks0) -> A.  gate 6, tail t=14 -> 3.
        if (t < NT_ - 2) {
            PPH({ issue_group(2 * t + 4); }, 6, fBx, fBw, { RD8(cbn, 0, fAx, fAw); });
        } else {
            PPH({}, 3, fBx, fBw, { RD8(cbn, 0, fAx, fAw); });
        }
    }
    {   // tile 15: p0 gate 0 (drain), read (15, ks1); p1 no read.
        char* cb = lds + ((NT_ - 1) & 1) * 49152;
        PPH({}, 0, fAx, fAw, { RD8(cb, 1, fBx, fBw); });
        PPH({}, -1, fBx, fBw, {});
    }
}

// ---------------------------------------------------------------------------
// Flash attention (causal), S^T/O^T, max-free softmax, register-resident P.
// (unchanged)
// ---------------------------------------------------------------------------
__global__ __launch_bounds__(256, 4) void attn_kernel(
    const u16* __restrict__ Qb, const u16* __restrict__ Kb,
    const u16* __restrict__ Vtb, u16* __restrict__ Yb)
{
    __shared__ u16 SMA[16384];       // Ks0|Ks1|Vs0|Vs1 (4x8KB), reused by epilogue
    u16* Ks0 = SMA;
    u16* Ks1 = SMA + 4096;
    u16* Vs0 = SMA + 8192;
    u16* Vs1 = SMA + 12288;

    int id = blockIdx.x;
    int bh = id & 63;
    int jj = id >> 6;                // 0..15

    int tid = threadIdx.x, lane = tid & 63, w = tid >> 6;
    int quad = lane >> 4, l15 = lane & 15;
    int b = bh >> 4, h = bh & 15;

    int koff0[4], koff1[4], voff[4][4];
#pragma unroll
    for (int sblk = 0; sblk < 4; ++sblk) {
        int sr = sblk * 16 + l15;
        koff0[sblk] = (sr * 64 + ((quad + sr) & 7) * 8) * 2;
        koff1[sblk] = (sr * 64 + ((4 + quad + sr) & 7) * 8) * 2;
    }
#pragma unroll
    for (int n = 0; n < 4; ++n)
#pragma unroll
        for (int sblk = 0; sblk < 4; ++sblk) {
            int dr = n * 16 + l15;
            voff[n][sblk] = (dr * 64 + ((sblk * 2 + (quad >> 1) + dr) & 7) * 8 + (quad & 1) * 4) * 2;
        }

    int cA = tid, cB = tid + 256;
    int sA = cA >> 3, sB = cB >> 3;
    int offA = (((cA & 7) - sA) & 7) * 8;
    int offB = (((cB & 7) - sB) & 7) * 8;
    const u16* Kbase = Kb + (size_t)(b * T_) * C_ + h * 64;
    const u16* Vbase = Vtb + (size_t)bh * D_ * T_;
    int ldsb0 = (w * 64) * 16, ldsb1 = (256 + w * 64) * 16;

    const s16x4 ones = { (short)0x3F80, (short)0x3F80, (short)0x3F80, (short)0x3F80 };
    const f32x4 z4 = {0.f, 0.f, 0.f, 0.f};

    int qts[2] = { jj, 31 - jj };

    for (int pass = 0; pass < 2; ++pass) {
        int qt = qts[pass];
        int qbase = qt * 64;

        if (pass) __syncthreads();

        bf16x8 qf0, qf1;
        {
            const u16* q0 = Qb + ((size_t)(b * T_ + qbase + w * 16 + l15)) * C_ + h * 64;
            qf0 = *(const bf16x8*)(q0 + quad * 8);
            qf1 = *(const bf16x8*)(q0 + 32 + quad * 8);
        }

        f32x4 o_acc[4];
        f32x4 l_acc = z4;
#pragma unroll
        for (int n = 0; n < 4; ++n) o_acc[n] = z4;

        const int nst = qt + 1;

        const u16* kgpA = Kbase + (size_t)sA * C_ + offA;
        const u16* kgpB = Kbase + (size_t)sB * C_ + offB;
        const u16* vgpA = Vbase + sA * T_ + offA;
        const u16* vgpB = Vbase + sB * T_ + offB;

        async16(kgpA, (char*)Ks0 + ldsb0);
        async16(kgpB, (char*)Ks0 + ldsb1);
        async16(vgpA, (char*)Vs0 + ldsb0);
        async16(vgpB, (char*)Vs0 + ldsb1);
        kgpA += 64 * C_; kgpB += 64 * C_; vgpA += 64; vgpB += 64;

        auto tile_body = [&](int st, const u16* K_, const u16* V_, char* Kpf, char* Vpf) {
            __syncthreads();
            if (st + 1 < nst) {
                async16(kgpA, Kpf + ldsb0);
                async16(kgpB, Kpf + ldsb1);
                async16(vgpA, Vpf + ldsb0);
                async16(vgpB, Vpf + ldsb1);
            }
            kgpA += 64 * C_; kgpB += 64 * C_; vgpA += 64; vgpB += 64;

            f32x4 sv[4];
#pragma unroll
            for (int sblk = 0; sblk < 4; ++sblk) {
                bf16x8 k0 = *(const bf16x8*)((const char*)K_ + koff0[sblk]);
                bf16x8 k1 = *(const bf16x8*)((const char*)K_ + koff1[sblk]);
                f32x4 t0 = __builtin_amdgcn_mfma_f32_16x16x32_bf16(k0, qf0, z4, 0, 0, 0);
                sv[sblk] = __builtin_amdgcn_mfma_f32_16x16x32_bf16(k1, qf1, t0, 0, 0, 0);
            }

            if (st == qt) {
                int tl = w * 16 + l15;
#pragma unroll
                for (int sblk = 0; sblk < 4; ++sblk)
#pragma unroll
                    for (int r = 0; r < 4; ++r)
                        if (sblk * 16 + quad * 4 + r > tl) sv[sblk][r] = -1e30f;
            }

            s16x4 pfrag[4];
#pragma unroll
            for (int sblk = 0; sblk < 4; ++sblk) {
#pragma unroll
                for (int r = 0; r < 4; ++r)
                    sv[sblk][r] = __builtin_amdgcn_exp2f(sv[sblk][r]);
                uint2 pk;
                pk.x = pk_bf16(sv[sblk][0], sv[sblk][1]);
                pk.y = pk_bf16(sv[sblk][2], sv[sblk][3]);
                pfrag[sblk] = *(s16x4*)&pk;
                l_acc = __builtin_amdgcn_mfma_f32_16x16x16bf16_1k(ones, pfrag[sblk], l_acc, 0, 0, 0);
            }

#pragma unroll
            for (int n = 0; n < 4; ++n)
#pragma unroll
                for (int sblk = 0; sblk < 4; ++sblk) {
                    s16x4 va = *(const s16x4*)((const char*)V_ + voff[n][sblk]);
                    o_acc[n] = __builtin_amdgcn_mfma_f32_16x16x16bf16_1k(va, pfrag[sblk], o_acc[n], 0, 0, 0);
                }
        };

        for (int st = 0; st < nst; st += 2) {
            tile_body(st, Ks0, Vs0, (char*)Ks1, (char*)Vs1);
            if (st + 1 < nst)
                tile_body(st + 1, Ks1, Vs1, (char*)Ks0, (char*)Vs0);
        }

        __syncthreads();
        u16* PW = SMA + w * 1152;
        {
            float inv = 1.0f / l_acc[0];
#pragma unroll
            for (int n = 0; n < 4; ++n) {
                uint2 pk;
                pk.x = pk_bf16(o_acc[n][0] * inv, o_acc[n][1] * inv);
                pk.y = pk_bf16(o_acc[n][2] * inv, o_acc[n][3] * inv);
                *(u16x4*)&PW[l15 * 72 + n * 16 + quad * 4] = *(u16x4*)&pk;
            }
        }
        asm volatile("s_waitcnt lgkmcnt(0)" ::: "memory");
#pragma unroll
        for (int st = 0; st < 2; ++st) {
            int tr = st * 8 + (lane >> 3);
            int d8 = (lane & 7) * 8;
            u16x8 v = *(u16x8*)&PW[tr * 72 + d8];
            *(u16x8*)&Yb[(size_t)(b * T_ + qbase + w * 16 + tr) * C_ + h * 64 + d8] = v;
        }
    }
}

// ---------------------------------------------------------------------------
// Output projection on the frag-ahead 2-phase core.
// Grid 256 = 8 XCD x 32 = exactly one residency round.
// ---------------------------------------------------------------------------
__global__ __launch_bounds__(512, 2) void proj_gemm8(
    const u16* __restrict__ Yb, const u16* __restrict__ Wob,
    const float* __restrict__ bo, float* __restrict__ out)
{
    __shared__ __attribute__((aligned(128))) char LDSRAW[98304];

    int id = blockIdx.x;
    int wg = (id & 7) * 32 + (id >> 3);
    int bm = wg >> 2, bn = wg & 3;
    int m0 = bm * 128, n0 = bn * 256;

    f32x4 acc[4][4];
    const f32x4 z4 = {0.f, 0.f, 0.f, 0.f};
#pragma unroll
    for (int i = 0; i < 4; ++i)
#pragma unroll
        for (int j = 0; j < 4; ++j) acc[i][j] = z4;

    gemm8p_core(Yb + (size_t)m0 * C_, Wob + (size_t)n0 * C_, LDSRAW, acc);

    int tid = threadIdx.x, lane = tid & 63, w = tid >> 6;
    int quad = lane >> 4, l15 = lane & 15;
    int wm = w >> 2, wn = w & 3;

#pragma unroll
    for (int j = 0; j < 4; ++j) {
        int ch = n0 + wn * 64 + j * 16 + quad * 4;
        f32x4 bv = *(const f32x4*)&bo[ch];
#pragma unroll
        for (int i = 0; i < 4; ++i) {
            int t = m0 + wm * 64 + i * 16 + l15;
            f32x4 v = acc[i][j] + bv;
            *(f32x4*)&out[(size_t)t * C_ + ch] = v;
        }
    }
}

// ---------------------------------------------------------------------------
// launch
// ---------------------------------------------------------------------------
extern "C" void kernel_launch(void* const* d_in, const int* in_sizes, int n_in,
                              void* d_out, int out_size, void* d_ws, size_t ws_size,
                              hipStream_t stream) {
    const float* X  = (const float*)d_in[0];
    const float* Wq = (const float*)d_in[1];
    const float* Wk = (const float*)d_in[2];
    const float* Wv = (const float*)d_in[3];
    const float* Wo = (const float*)d_in[4];
    const float* bo = (const float*)d_in[5];

    char* ws = (char*)d_ws;
    u16* Xb  = (u16*)(ws);                       // 16 MB  [BT, C] bf16
    u16* Wqb = (u16*)(ws + (16u << 20));         //  2 MB  } contiguous
    u16* Wkb = (u16*)(ws + (18u << 20));         //  2 MB  } [3072,1024]
    u16* Wvb = (u16*)(ws + (20u << 20));         //  2 MB  } Wcat
    u16* Wob = (u16*)(ws + (22u << 20));         //  2 MB
    u16* Qb  = (u16*)(ws + (24u << 20));         // 16 MB  [BT, C] (pre-scaled)
    u16* Kb  = (u16*)(ws + (40u << 20));         // 16 MB  [BT, C]
    u16* Vtb = (u16*)(ws + (56u << 20));         // 16 MB  [B,H,D,T]
    u16* Yb  = (u16*)(ws + (72u << 20));         // 16 MB  [BT, C]

    cast_all_kernel<<<dim3(8192 + 4 * 1024), 256, 0, stream>>>(
        X, Wq, Wk, Wv, Wo, Xb, Wqb, Wkb, Wvb, Wob);

    qkv_gemm384<<<dim3(512), 512, 0, stream>>>(Xb, Wqb, Qb, Kb, Vtb);
    attn_kernel<<<dim3(1024), 256, 0, stream>>>(Qb, Kb, Vtb, Yb);
    proj_gemm8<<<dim3(256), 512, 0, stream>>>(Yb, Wob, bo, (float*)d_out);
}

// Round 5
// 226.502 us; speedup vs baseline: 1.0150x; 1.0150x over previous
//
#include <hip/hip_runtime.h>
#include <hip/hip_bf16.h>
#include <stdint.h>

// ---------------------------------------------------------------------------
// SplitCausalSelfAttention on MI355X (gfx950), bf16 MFMA implementation.
// B=4, T=2048, C=1024, H=16, D=64.
// R16: mixed-size grid for qkv.  R13's 4-phase 256x256 core is the best
//      per-area core measured (0.084 cyc/elem/ktile) but 384 tiles = 1.5
//      rounds at 1 blk/CU wasted a half-empty round.  Now: 256 full 256^2
//      Q/K tiles (cols 0..2047, round 1) + 256 half 128x256 V tiles
//      (cols 2048..3071 m-split, round 2 at tau/2) = wall 1.5*tau.
//      Half-core: 2 barriers + 1 counted vmcnt(6) gate per K-tile
//      (issue all t+1 units at t-top into other dbuf; gate waits own tile;
//      barrier publishes; reads; 32 MFMA; trail barrier = WAR fence).
//      Full core = R13 verbatim.  attn/proj/cast unchanged.
// ---------------------------------------------------------------------------

typedef unsigned short u16;
typedef __attribute__((ext_vector_type(8))) __bf16 bf16x8;  // 4 VGPRs (A/B frag, K=32)
typedef __attribute__((ext_vector_type(4))) float  f32x4;   // C/D frag
typedef __attribute__((ext_vector_type(4))) unsigned short u16x4;
typedef __attribute__((ext_vector_type(8))) unsigned short u16x8;
typedef __attribute__((ext_vector_type(4))) short s16x4;    // 2 VGPRs (A/B frag, K=16)

#define B_  4
#define T_  2048
#define C_  1024
#define H_  16
#define D_  64
#define BT_ (B_ * T_)
#define NT_ 16        // K-tiles of 64 over K=1024

// scale = 1/sqrt(D) folded with log2(e) so softmax uses exp2
#define Q_SCALE 0.1803368801111204f

__device__ __forceinline__ u16 f32_to_bf16(float f) {
    unsigned int u = __float_as_uint(f);
    unsigned int r = (u + 0x7FFFu + ((u >> 16) & 1u)) >> 16;
    return (u16)r;
}

__device__ __forceinline__ unsigned int pk_bf16(float a, float b) {
    float2 f2; f2.x = a; f2.y = b;
    __hip_bfloat162 h = __float22bfloat162_rn(f2);
    return *(unsigned int*)&h;
}

__device__ __forceinline__ void async16(const void* g, void* lds) {
    __builtin_amdgcn_global_load_lds(
        (const __attribute__((address_space(1))) void*)g,
        (__attribute__((address_space(3))) void*)lds, 16, 0, 0);
}

// ---------------------------------------------------------------------------
// single cast kernel: X (8192 blocks) + 4 weights (1024 blocks each)
// ---------------------------------------------------------------------------
__global__ void cast_all_kernel(const float* __restrict__ X,
                                const float* __restrict__ w0, const float* __restrict__ w1,
                                const float* __restrict__ w2, const float* __restrict__ w3,
                                u16* __restrict__ xo,
                                u16* __restrict__ o0, u16* __restrict__ o1,
                                u16* __restrict__ o2, u16* __restrict__ o3) {
    int id = blockIdx.x;
    const float* in; u16* out; int i;
    if (id < 8192) {
        in = X; out = xo; i = id * 256 + threadIdx.x;
    } else {
        int k = (id - 8192) >> 10;
        in  = (k == 0) ? w0 : (k == 1) ? w1 : (k == 2) ? w2 : w3;
        out = (k == 0) ? o0 : (k == 1) ? o1 : (k == 2) ? o2 : o3;
        i = ((id - 8192) & 1023) * 256 + threadIdx.x;
    }
    float4 v = ((const float4*)in)[i];
    u16x4 o;
    o[0] = f32_to_bf16(v.x); o[1] = f32_to_bf16(v.y);
    o[2] = f32_to_bf16(v.z); o[3] = f32_to_bf16(v.w);
    ((u16x4*)out)[i] = o;
}

// ---------------------------------------------------------------------------
// Full-tile 256x256 4-phase core (R13, non-swap only).
// LDS: dbuf d at d*65536; unit u at u*16384 (u0=A rows 0-127, u1=A 128-255,
// u2=B rows 0-127, u3=B 128-255).  Row r at r*128B, 8 slots of 16B; slot
// holds k-group (slot-r)&7 (k-rotation swizzle, measured 0-conflict).
// Phase (mh,nh) reads units {mh, 2+nh}; issue order u0,u2,u3,u1 into the
// other dbuf; vmcnt(4) gates at p0/p1/p3.  Residency/WAR ledger: R13 notes.
// ---------------------------------------------------------------------------
#define QPHASE(CB, MH, NH, DOISSUE, G, GATE)                                      \
  {                                                                               \
    if ((NH) == 0) {                                                              \
      _Pragma("unroll")                                                           \
      for (int f = 0; f < 4; ++f) {                                               \
        _Pragma("unroll")                                                         \
        for (int ks = 0; ks < 2; ++ks)                                            \
          xf[f][ks] = *(const bf16x8*)((CB) + (MH) * 16384 + axoff[f][ks]);       \
      }                                                                           \
    }                                                                             \
    if ((MH) == 0) {                                                              \
      _Pragma("unroll")                                                           \
      for (int e = 0; e < 2; ++e) {                                               \
        _Pragma("unroll")                                                         \
        for (int ks = 0; ks < 2; ++ks)                                            \
          wf[NH][e][ks] = *(const bf16x8*)((CB) + (NH) * 16384 + bwoff[e][ks]);   \
      }                                                                           \
    }                                                                             \
    if (DOISSUE) issue_unit(G);                                                   \
    if ((GATE) == 4)      asm volatile("s_waitcnt vmcnt(4)" ::: "memory");        \
    else if ((GATE) == 2) asm volatile("s_waitcnt vmcnt(2)" ::: "memory");        \
    else if ((GATE) == 0) asm volatile("s_waitcnt vmcnt(0)" ::: "memory");        \
    __builtin_amdgcn_s_barrier();                                                 \
    asm volatile("" ::: "memory");                                                \
    __builtin_amdgcn_s_setprio(1);                                                \
    _Pragma("unroll")                                                             \
    for (int f = 0; f < 4; ++f) {                                                 \
      _Pragma("unroll")                                                           \
      for (int e = 0; e < 2; ++e) {                                               \
        f32x4 a_ = acc[(MH) * 4 + f][(NH) * 2 + e];                               \
        a_ = __builtin_amdgcn_mfma_f32_16x16x32_bf16(wf[NH][e][0], xf[f][0], a_, 0, 0, 0); \
        a_ = __builtin_amdgcn_mfma_f32_16x16x32_bf16(wf[NH][e][1], xf[f][1], a_, 0, 0, 0); \
        acc[(MH) * 4 + f][(NH) * 2 + e] = a_;                                     \
      }                                                                           \
    }                                                                             \
    __builtin_amdgcn_s_setprio(0);                                                \
    asm volatile("" ::: "memory");                                                \
    __builtin_amdgcn_s_barrier();                                                 \
    asm volatile("" ::: "memory");                                                \
  }

__device__ __forceinline__ void qkv256_core(const u16* __restrict__ Arow,
                                            const u16* __restrict__ Brow,
                                            char* lds, f32x4 (&acc)[8][4])
{
    int tid = threadIdx.x, lane = tid & 63, w = tid >> 6;
    int quad = lane >> 4, l15 = lane & 15;
    int wm = w >> 2, wn = w & 3;

    int gc = (((tid & 7) - (tid >> 3)) & 7) * 8;
    const u16* xsrc0 = Arow + (size_t)(tid >> 3) * C_ + gc;
    const u16* xsrc1 = xsrc0 + (size_t)64 * C_;
    const u16* wsrc0 = Brow + (size_t)(tid >> 3) * C_ + gc;
    const u16* wsrc1 = wsrc0 + (size_t)64 * C_;

    auto issue_unit = [&](int g) {
        int u = g & 3, kt = g >> 2;
        char* d = lds + ((kt & 1) << 16) + (u << 14) + (w << 10);
        size_t off = (size_t)(u & 1) * (128 * C_) + (size_t)kt * 64;
        const u16* s0 = (u < 2) ? xsrc0 : wsrc0;
        const u16* s1 = (u < 2) ? xsrc1 : wsrc1;
        async16(s0 + off, d);
        async16(s1 + off, d + 8192);
    };

    int axoff[4][2], bwoff[2][2];
#pragma unroll
    for (int f = 0; f < 4; ++f) {
        int r = wm * 64 + f * 16 + l15;
#pragma unroll
        for (int ks = 0; ks < 2; ++ks)
            axoff[f][ks] = r * 128 + (((ks * 4 + quad + r) & 7) << 4);
    }
#pragma unroll
    for (int e = 0; e < 2; ++e) {
        int r = wn * 32 + e * 16 + l15;
#pragma unroll
        for (int ks = 0; ks < 2; ++ks)
            bwoff[e][ks] = 32768 + r * 128 + (((ks * 4 + quad + r) & 7) << 4);
    }

    bf16x8 xf[4][2];       // A-frags for current mh (read at nh==0 phases)
    bf16x8 wf[2][2][2];    // B-frags for both nh (read at mh==0 phases)

    issue_unit(0); issue_unit(2); issue_unit(3); issue_unit(1);
    asm volatile("s_waitcnt vmcnt(4)" ::: "memory");
    __builtin_amdgcn_s_barrier();
    asm volatile("" ::: "memory");

    for (int t = 0; t < NT_ - 1; ++t) {
        char* cb = lds + ((t & 1) << 16);
        int g4 = (t + 1) << 2;
        QPHASE(cb, 0, 0, 1, g4 + 0, 4);    // reads u0,u2; issue next.u0
        QPHASE(cb, 0, 1, 1, g4 + 2, 4);    // reads u3;    issue next.u2
        QPHASE(cb, 1, 0, 1, g4 + 3, -1);   // reads u1;    issue next.u3
        QPHASE(cb, 1, 1, 1, g4 + 1, 4);    // pure reg;    issue next.u1
    }
    {   // peeled last tile (15, odd -> dbuf 1): tail drain 2 -> 0
        char* cb = lds + 65536;
        QPHASE(cb, 0, 0, 0, 0, 2);
        QPHASE(cb, 0, 1, 0, 0, 0);
        QPHASE(cb, 1, 0, 0, 0, -1);
        QPHASE(cb, 1, 1, 0, 0, -1);
    }
}

// ---------------------------------------------------------------------------
// Half-tile 128x256 core (V panels, swapped operands).  Units u0 (A, the
// half's 128 rows), u2/u3 (B rows 0-127/128-255); same LDS geometry and
// swizzle as the full core; u1 unused.  Per K-tile: issue all 6 loads of
// t+1 into other dbuf; gate vmcnt(6) (= wait own tile t; tail t=15 -> 0);
// barrier (publish); read xf + wf0, 16 MFMA; read wf1, 16 MFMA; barrier
// (WAR fence for t+2's issue).  Prefetch window = 1 tile (~2000+ cyc).
// ---------------------------------------------------------------------------
__device__ __forceinline__ void qkv128v_core(const u16* __restrict__ Arow,
                                             const u16* __restrict__ Brow,
                                             char* lds, f32x4 (&acc)[4][4])
{
    int tid = threadIdx.x, lane = tid & 63, w = tid >> 6;
    int quad = lane >> 4, l15 = lane & 15;
    int wm = w >> 2, wn = w & 3;

    int gc = (((tid & 7) - (tid >> 3)) & 7) * 8;
    const u16* asrc  = Arow + (size_t)(tid >> 3) * C_ + gc;
    const u16* bsrc0 = Brow + (size_t)(tid >> 3) * C_ + gc;
    const u16* bsrc1 = bsrc0 + (size_t)64 * C_;

    auto issue3 = [&](int kt) {
        char* db = lds + ((kt & 1) << 16) + (w << 10);
        int ko = kt * 64;
        // u0: A rows 0..127 of the half
        async16(asrc + ko,                       db);
        async16(asrc + ko + (size_t)64 * C_,     db + 8192);
        // u2: B rows 0..127
        async16(bsrc0 + ko,                      db + 32768);
        async16(bsrc1 + ko,                      db + 32768 + 8192);
        // u3: B rows 128..255
        async16(bsrc0 + ko + (size_t)128 * C_,   db + 49152);
        async16(bsrc1 + ko + (size_t)128 * C_,   db + 49152 + 8192);
    };

    int axoff[4][2], bwoff[2][2];
#pragma unroll
    for (int f = 0; f < 4; ++f) {
        int r = wm * 64 + f * 16 + l15;
#pragma unroll
        for (int ks = 0; ks < 2; ++ks)
            axoff[f][ks] = r * 128 + (((ks * 4 + quad + r) & 7) << 4);
    }
#pragma unroll
    for (int e = 0; e < 2; ++e) {
        int r = wn * 32 + e * 16 + l15;
#pragma unroll
        for (int ks = 0; ks < 2; ++ks)
            bwoff[e][ks] = 32768 + r * 128 + (((ks * 4 + quad + r) & 7) << 4);
    }

    bf16x8 xf[4][2], wf[2][2];

    issue3(0);          // prologue: tile 0 (6 loads/thread)

    for (int t = 0; t < NT_; ++t) {
        char* cb = lds + ((t & 1) << 16);
        if (t + 1 < NT_) issue3(t + 1);                 // other dbuf; WAR ok
        if (t == NT_ - 1) asm volatile("s_waitcnt vmcnt(0)" ::: "memory");
        else              asm volatile("s_waitcnt vmcnt(6)" ::: "memory");
        __builtin_amdgcn_s_barrier();                   // publish tile t
        asm volatile("" ::: "memory");

        // nh = 0: units u0 + u2
#pragma unroll
        for (int f = 0; f < 4; ++f)
#pragma unroll
            for (int ks = 0; ks < 2; ++ks)
                xf[f][ks] = *(const bf16x8*)(cb + axoff[f][ks]);
#pragma unroll
        for (int e = 0; e < 2; ++e)
#pragma unroll
            for (int ks = 0; ks < 2; ++ks)
                wf[e][ks] = *(const bf16x8*)(cb + bwoff[e][ks]);
        __builtin_amdgcn_s_setprio(1);
#pragma unroll
        for (int f = 0; f < 4; ++f)
#pragma unroll
            for (int e = 0; e < 2; ++e) {
                f32x4 a_ = acc[f][e];
                a_ = __builtin_amdgcn_mfma_f32_16x16x32_bf16(xf[f][0], wf[e][0], a_, 0, 0, 0);
                a_ = __builtin_amdgcn_mfma_f32_16x16x32_bf16(xf[f][1], wf[e][1], a_, 0, 0, 0);
                acc[f][e] = a_;
            }
        __builtin_amdgcn_s_setprio(0);

        // nh = 1: unit u3 (xf register-reused)
#pragma unroll
        for (int e = 0; e < 2; ++e)
#pragma unroll
            for (int ks = 0; ks < 2; ++ks)
                wf[e][ks] = *(const bf16x8*)(cb + 16384 + bwoff[e][ks]);
        __builtin_amdgcn_s_setprio(1);
#pragma unroll
        for (int f = 0; f < 4; ++f)
#pragma unroll
            for (int e = 0; e < 2; ++e) {
                f32x4 a_ = acc[f][2 + e];
                a_ = __builtin_amdgcn_mfma_f32_16x16x32_bf16(xf[f][0], wf[e][0], a_, 0, 0, 0);
                a_ = __builtin_amdgcn_mfma_f32_16x16x32_bf16(xf[f][1], wf[e][1], a_, 0, 0, 0);
                acc[f][2 + e] = a_;
            }
        __builtin_amdgcn_s_setprio(0);
        asm volatile("" ::: "memory");
        __builtin_amdgcn_s_barrier();                   // WAR fence
        asm volatile("" ::: "memory");
    }
}

// ---------------------------------------------------------------------------
// Fused QKV, mixed grid 512:
//  id 0..255  : full 256x256 Q/K tiles.  ti=(id&7)*32+(id>>3): bn=ti>>5
//               (= XCD, W panel L2-pinned), bm=ti&31.  cols 0..2047.
//  id 256..511: half 128x256 V tiles.  hw=(id2&7)*32+(id2>>3): vt=hw>>6
//               (V n-tile, 2 XCDs/panel), bm=(hw&63)>>1, half=hw&1.
// ---------------------------------------------------------------------------
__global__ __launch_bounds__(512, 2) void qkv_mix512(
    const u16* __restrict__ Xb, const u16* __restrict__ Wcat,
    u16* __restrict__ Qb, u16* __restrict__ Kb, u16* __restrict__ Vtb)
{
    __shared__ __attribute__((aligned(128))) char LDSRAW[131072];

    int id = blockIdx.x;
    int tid = threadIdx.x, lane = tid & 63, w = tid >> 6;
    int quad = lane >> 4, l15 = lane & 15;
    int wm = w >> 2, wn = w & 3;

    if (id < 256) {
        int ti = (id & 7) * 32 + (id >> 3);
        int bm = ti & 31, bn = ti >> 5;          // bn == id&7 == XCD
        int m0 = bm * 256, chb = bn * 256;       // cols 0..2047 (Q|K)

        f32x4 acc[8][4];
        const f32x4 z4 = {0.f, 0.f, 0.f, 0.f};
#pragma unroll
        for (int i = 0; i < 8; ++i)
#pragma unroll
            for (int j = 0; j < 4; ++j) acc[i][j] = z4;

        qkv256_core(Xb + (size_t)m0 * C_, Wcat + (size_t)chb * C_, LDSRAW, acc);

        // Q/K epilogue: D row = ch (quad*4+rr), col = t (l15)
#pragma unroll
        for (int mi = 0; mi < 8; ++mi) {
            size_t trow = (size_t)(m0 + (mi >> 2) * 128 + wm * 64 + (mi & 3) * 16 + l15) * C_;
#pragma unroll
            for (int nj = 0; nj < 4; ++nj) {
                int colb = chb + (nj >> 1) * 128 + wn * 32 + (nj & 1) * 16 + quad * 4;
                u16* OUT = (colb < 1024) ? Qb : Kb;
                float sc = (colb < 1024) ? Q_SCALE : 1.0f;
                u16x4 v;
#pragma unroll
                for (int rr = 0; rr < 4; ++rr) v[rr] = f32_to_bf16(acc[mi][nj][rr] * sc);
                *(u16x4*)&OUT[trow + (colb & 1023)] = v;
            }
        }
    } else {
        int id2 = id - 256;
        int hw = (id2 & 7) * 32 + (id2 >> 3);
        int vt = hw >> 6;                        // 0..3 (V n-tile)
        int bm = (hw & 63) >> 1, half = hw & 1;
        int m0h = bm * 256 + half * 128;
        int chb = 2048 + vt * 256;               // cols 2048..3071 (V)

        f32x4 acc[4][4];
        const f32x4 z4 = {0.f, 0.f, 0.f, 0.f};
#pragma unroll
        for (int i = 0; i < 4; ++i)
#pragma unroll
            for (int j = 0; j < 4; ++j) acc[i][j] = z4;

        qkv128v_core(Xb + (size_t)m0h * C_, Wcat + (size_t)chb * C_, LDSRAW, acc);

        // V epilogue (swapped): D row = t (quad*4+rr), col = ch (l15) -> [B,H,D,T]
#pragma unroll
        for (int mi = 0; mi < 4; ++mi) {
            int t0 = m0h + wm * 64 + mi * 16 + quad * 4;
            int b_ = t0 >> 11, tl = t0 & (T_ - 1);
#pragma unroll
            for (int nj = 0; nj < 4; ++nj) {
                int ch = chb + (nj >> 1) * 128 + wn * 32 + (nj & 1) * 16 + l15;
                int h = (ch >> 6) & 15, d = ch & 63;
                u16x4 v;
#pragma unroll
                for (int rr = 0; rr < 4; ++rr) v[rr] = f32_to_bf16(acc[mi][nj][rr]);
                *(u16x4*)&Vtb[((size_t)(b_ * H_ + h) * D_ + d) * T_ + tl] = v;
            }
        }
    }
}

// ---------------------------------------------------------------------------
// proj 2-phase pipelined core with frag-ahead (unchanged from R15).
// ---------------------------------------------------------------------------
#define RD8(CB, KS, FX, FW)                                                      \
    _Pragma("unroll") for (int i_ = 0; i_ < 4; ++i_) {                           \
        FX[i_] = *(const bf16x8*)((CB) + (KS) * 8192  + xoff[i_]);               \
        FW[i_] = *(const bf16x8*)((CB) + (KS) * 16384 + woff[i_]);               \
    }

#define PPH(ISSUE, GATE, FX, FW, ...)                                            \
  {                                                                              \
    ISSUE;                                                                       \
    if ((GATE) == 6)      asm volatile("s_waitcnt vmcnt(6)" ::: "memory");       \
    else if ((GATE) == 3) asm volatile("s_waitcnt vmcnt(3)" ::: "memory");       \
    else if ((GATE) == 0) asm volatile("s_waitcnt vmcnt(0)" ::: "memory");       \
    __builtin_amdgcn_s_barrier();                                                \
    asm volatile("" ::: "memory");                                               \
    __VA_ARGS__;                                                                 \
    __builtin_amdgcn_sched_barrier(0);                                           \
    __builtin_amdgcn_s_setprio(1);                                               \
    _Pragma("unroll") for (int i = 0; i < 4; ++i)                                \
      _Pragma("unroll") for (int j = 0; j < 4; ++j)                              \
        acc[i][j] = __builtin_amdgcn_mfma_f32_16x16x32_bf16(FW[j], FX[i], acc[i][j], 0, 0, 0); \
    __builtin_amdgcn_s_setprio(0);                                               \
    asm volatile("" ::: "memory");                                               \
    __builtin_amdgcn_s_barrier();                                                \
    asm volatile("" ::: "memory");                                               \
  }

__device__ __forceinline__ void gemm8p_core(const u16* __restrict__ Arow,
                                            const u16* __restrict__ Brow,
                                            char* lds, f32x4 (&acc)[4][4])
{
    int tid  = threadIdx.x;
    int lane = tid & 63, w = tid >> 6;
    int quad = lane >> 4, l15 = lane & 15;
    int wm = w >> 2, wn = w & 3;

    int r  = tid >> 2, s4 = tid & 3;
    int kg = ((s4 - (r >> 1)) & 3) * 8;
    const u16* xsrc  = Arow + (size_t)r * C_ + kg;
    const u16* wsrc0 = Brow + (size_t)r * C_ + kg;
    const u16* wsrc1 = Brow + (size_t)(128 + r) * C_ + kg;
    int wu = w << 10;

    int xoff[4], woff[4];
#pragma unroll
    for (int i = 0; i < 4; ++i) {
        int rx = wm * 64 + i * 16 + l15;
        xoff[i] = rx * 64 + (((rx >> 1) + quad) & 3) * 16;
        int rw = wn * 64 + i * 16 + l15;
        woff[i] = 16384 + rw * 64 + (((rw >> 1) + quad) & 3) * 16;
    }

    auto issue_group = [&](int g) {
        int db = (g >> 1) & 1, ks = g & 1;
        int koff = (g >> 1) * 64 + ks * 32;
        char* ldb = lds + db * 49152;
        async16(xsrc  + koff, ldb + ks * 8192 + wu);
        async16(wsrc0 + koff, ldb + 16384 + ks * 16384 + wu);
        async16(wsrc1 + koff, ldb + 16384 + ks * 16384 + 8192 + wu);
    };

    bf16x8 fAx[4], fAw[4], fBx[4], fBw[4];

    issue_group(0); issue_group(1); issue_group(2);
    asm volatile("s_waitcnt vmcnt(6)" ::: "memory");
    __builtin_amdgcn_s_barrier();
    asm volatile("" ::: "memory");
    RD8(lds, 0, fAx, fAw);

    for (int t = 0; t < NT_ - 1; ++t) {
        char* cb  = lds + (t & 1) * 49152;
        char* cbn = lds + ((t + 1) & 1) * 49152;
        PPH({ issue_group(2 * t + 3); }, 6, fAx, fAw, { RD8(cb, 1, fBx, fBw); });
        if (t < NT_ - 2) {
            PPH({ issue_group(2 * t + 4); }, 6, fBx, fBw, { RD8(cbn, 0, fAx, fAw); });
        } else {
            PPH({}, 3, fBx, fBw, { RD8(cbn, 0, fAx, fAw); });
        }
    }
    {
        char* cb = lds + ((NT_ - 1) & 1) * 49152;
        PPH({}, 0, fAx, fAw, { RD8(cb, 1, fBx, fBw); });
        PPH({}, -1, fBx, fBw, {});
    }
}

// ---------------------------------------------------------------------------
// Flash attention (causal), S^T/O^T, max-free softmax, register-resident P.
// (unchanged)
// ---------------------------------------------------------------------------
__global__ __launch_bounds__(256, 4) void attn_kernel(
    const u16* __restrict__ Qb, const u16* __restrict__ Kb,
    const u16* __restrict__ Vtb, u16* __restrict__ Yb)
{
    __shared__ u16 SMA[16384];       // Ks0|Ks1|Vs0|Vs1 (4x8KB), reused by epilogue
    u16* Ks0 = SMA;
    u16* Ks1 = SMA + 4096;
    u16* Vs0 = SMA + 8192;
    u16* Vs1 = SMA + 12288;

    int id = blockIdx.x;
    int bh = id & 63;
    int jj = id >> 6;                // 0..15

    int tid = threadIdx.x, lane = tid & 63, w = tid >> 6;
    int quad = lane >> 4, l15 = lane & 15;
    int b = bh >> 4, h = bh & 15;

    int koff0[4], koff1[4], voff[4][4];
#pragma unroll
    for (int sblk = 0; sblk < 4; ++sblk) {
        int sr = sblk * 16 + l15;
        koff0[sblk] = (sr * 64 + ((quad + sr) & 7) * 8) * 2;
        koff1[sblk] = (sr * 64 + ((4 + quad + sr) & 7) * 8) * 2;
    }
#pragma unroll
    for (int n = 0; n < 4; ++n)
#pragma unroll
        for (int sblk = 0; sblk < 4; ++sblk) {
            int dr = n * 16 + l15;
            voff[n][sblk] = (dr * 64 + ((sblk * 2 + (quad >> 1) + dr) & 7) * 8 + (quad & 1) * 4) * 2;
        }

    int cA = tid, cB = tid + 256;
    int sA = cA >> 3, sB = cB >> 3;
    int offA = (((cA & 7) - sA) & 7) * 8;
    int offB = (((cB & 7) - sB) & 7) * 8;
    const u16* Kbase = Kb + (size_t)(b * T_) * C_ + h * 64;
    const u16* Vbase = Vtb + (size_t)bh * D_ * T_;
    int ldsb0 = (w * 64) * 16, ldsb1 = (256 + w * 64) * 16;

    const s16x4 ones = { (short)0x3F80, (short)0x3F80, (short)0x3F80, (short)0x3F80 };
    const f32x4 z4 = {0.f, 0.f, 0.f, 0.f};

    int qts[2] = { jj, 31 - jj };

    for (int pass = 0; pass < 2; ++pass) {
        int qt = qts[pass];
        int qbase = qt * 64;

        if (pass) __syncthreads();

        bf16x8 qf0, qf1;
        {
            const u16* q0 = Qb + ((size_t)(b * T_ + qbase + w * 16 + l15)) * C_ + h * 64;
            qf0 = *(const bf16x8*)(q0 + quad * 8);
            qf1 = *(const bf16x8*)(q0 + 32 + quad * 8);
        }

        f32x4 o_acc[4];
        f32x4 l_acc = z4;
#pragma unroll
        for (int n = 0; n < 4; ++n) o_acc[n] = z4;

        const int nst = qt + 1;

        const u16* kgpA = Kbase + (size_t)sA * C_ + offA;
        const u16* kgpB = Kbase + (size_t)sB * C_ + offB;
        const u16* vgpA = Vbase + sA * T_ + offA;
        const u16* vgpB = Vbase + sB * T_ + offB;

        async16(kgpA, (char*)Ks0 + ldsb0);
        async16(kgpB, (char*)Ks0 + ldsb1);
        async16(vgpA, (char*)Vs0 + ldsb0);
        async16(vgpB, (char*)Vs0 + ldsb1);
        kgpA += 64 * C_; kgpB += 64 * C_; vgpA += 64; vgpB += 64;

        auto tile_body = [&](int st, const u16* K_, const u16* V_, char* Kpf, char* Vpf) {
            __syncthreads();
            if (st + 1 < nst) {
                async16(kgpA, Kpf + ldsb0);
                async16(kgpB, Kpf + ldsb1);
                async16(vgpA, Vpf + ldsb0);
                async16(vgpB, Vpf + ldsb1);
            }
            kgpA += 64 * C_; kgpB += 64 * C_; vgpA += 64; vgpB += 64;

            f32x4 sv[4];
#pragma unroll
            for (int sblk = 0; sblk < 4; ++sblk) {
                bf16x8 k0 = *(const bf16x8*)((const char*)K_ + koff0[sblk]);
                bf16x8 k1 = *(const bf16x8*)((const char*)K_ + koff1[sblk]);
                f32x4 t0 = __builtin_amdgcn_mfma_f32_16x16x32_bf16(k0, qf0, z4, 0, 0, 0);
                sv[sblk] = __builtin_amdgcn_mfma_f32_16x16x32_bf16(k1, qf1, t0, 0, 0, 0);
            }

            if (st == qt) {
                int tl = w * 16 + l15;
#pragma unroll
                for (int sblk = 0; sblk < 4; ++sblk)
#pragma unroll
                    for (int r = 0; r < 4; ++r)
                        if (sblk * 16 + quad * 4 + r > tl) sv[sblk][r] = -1e30f;
            }

            s16x4 pfrag[4];
#pragma unroll
            for (int sblk = 0; sblk < 4; ++sblk) {
#pragma unroll
                for (int r = 0; r < 4; ++r)
                    sv[sblk][r] = __builtin_amdgcn_exp2f(sv[sblk][r]);
                uint2 pk;
                pk.x = pk_bf16(sv[sblk][0], sv[sblk][1]);
                pk.y = pk_bf16(sv[sblk][2], sv[sblk][3]);
                pfrag[sblk] = *(s16x4*)&pk;
                l_acc = __builtin_amdgcn_mfma_f32_16x16x16bf16_1k(ones, pfrag[sblk], l_acc, 0, 0, 0);
            }

#pragma unroll
            for (int n = 0; n < 4; ++n)
#pragma unroll
                for (int sblk = 0; sblk < 4; ++sblk) {
                    s16x4 va = *(const s16x4*)((const char*)V_ + voff[n][sblk]);
                    o_acc[n] = __builtin_amdgcn_mfma_f32_16x16x16bf16_1k(va, pfrag[sblk], o_acc[n], 0, 0, 0);
                }
        };

        for (int st = 0; st < nst; st += 2) {
            tile_body(st, Ks0, Vs0, (char*)Ks1, (char*)Vs1);
            if (st + 1 < nst)
                tile_body(st + 1, Ks1, Vs1, (char*)Ks0, (char*)Vs0);
        }

        __syncthreads();
        u16* PW = SMA + w * 1152;
        {
            float inv = 1.0f / l_acc[0];
#pragma unroll
            for (int n = 0; n < 4; ++n) {
                uint2 pk;
                pk.x = pk_bf16(o_acc[n][0] * inv, o_acc[n][1] * inv);
                pk.y = pk_bf16(o_acc[n][2] * inv, o_acc[n][3] * inv);
                *(u16x4*)&PW[l15 * 72 + n * 16 + quad * 4] = *(u16x4*)&pk;
            }
        }
        asm volatile("s_waitcnt lgkmcnt(0)" ::: "memory");
#pragma unroll
        for (int st = 0; st < 2; ++st) {
            int tr = st * 8 + (lane >> 3);
            int d8 = (lane & 7) * 8;
            u16x8 v = *(u16x8*)&PW[tr * 72 + d8];
            *(u16x8*)&Yb[(size_t)(b * T_ + qbase + w * 16 + tr) * C_ + h * 64 + d8] = v;
        }
    }
}

// ---------------------------------------------------------------------------
// Output projection on the frag-ahead 2-phase core (unchanged).
// Grid 256 = 8 XCD x 32 = exactly one residency round.
// ---------------------------------------------------------------------------
__global__ __launch_bounds__(512, 2) void proj_gemm8(
    const u16* __restrict__ Yb, const u16* __restrict__ Wob,
    const float* __restrict__ bo, float* __restrict__ out)
{
    __shared__ __attribute__((aligned(128))) char LDSRAW[98304];

    int id = blockIdx.x;
    int wg = (id & 7) * 32 + (id >> 3);
    int bm = wg >> 2, bn = wg & 3;
    int m0 = bm * 128, n0 = bn * 256;

    f32x4 acc[4][4];
    const f32x4 z4 = {0.f, 0.f, 0.f, 0.f};
#pragma unroll
    for (int i = 0; i < 4; ++i)
#pragma unroll
        for (int j = 0; j < 4; ++j) acc[i][j] = z4;

    gemm8p_core(Yb + (size_t)m0 * C_, Wob + (size_t)n0 * C_, LDSRAW, acc);

    int tid = threadIdx.x, lane = tid & 63, w = tid >> 6;
    int quad = lane >> 4, l15 = lane & 15;
    int wm = w >> 2, wn = w & 3;

#pragma unroll
    for (int j = 0; j < 4; ++j) {
        int ch = n0 + wn * 64 + j * 16 + quad * 4;
        f32x4 bv = *(const f32x4*)&bo[ch];
#pragma unroll
        for (int i = 0; i < 4; ++i) {
            int t = m0 + wm * 64 + i * 16 + l15;
            f32x4 v = acc[i][j] + bv;
            *(f32x4*)&out[(size_t)t * C_ + ch] = v;
        }
    }
}

// ---------------------------------------------------------------------------
// launch
// ---------------------------------------------------------------------------
extern "C" void kernel_launch(void* const* d_in, const int* in_sizes, int n_in,
                              void* d_out, int out_size, void* d_ws, size_t ws_size,
                              hipStream_t stream) {
    const float* X  = (const float*)d_in[0];
    const float* Wq = (const float*)d_in[1];
    const float* Wk = (const float*)d_in[2];
    const float* Wv = (const float*)d_in[3];
    const float* Wo = (const float*)d_in[4];
    const float* bo = (const float*)d_in[5];

    char* ws = (char*)d_ws;
    u16* Xb  = (u16*)(ws);                       // 16 MB  [BT, C] bf16
    u16* Wqb = (u16*)(ws + (16u << 20));         //  2 MB  } contiguous
    u16* Wkb = (u16*)(ws + (18u << 20));         //  2 MB  } [3072,1024]
    u16* Wvb = (u16*)(ws + (20u << 20));         //  2 MB  } Wcat
    u16* Wob = (u16*)(ws + (22u << 20));         //  2 MB
    u16* Qb  = (u16*)(ws + (24u << 20));         // 16 MB  [BT, C] (pre-scaled)
    u16* Kb  = (u16*)(ws + (40u << 20));         // 16 MB  [BT, C]
    u16* Vtb = (u16*)(ws + (56u << 20));         // 16 MB  [B,H,D,T]
    u16* Yb  = (u16*)(ws + (72u << 20));         // 16 MB  [BT, C]

    cast_all_kernel<<<dim3(8192 + 4 * 1024), 256, 0, stream>>>(
        X, Wq, Wk, Wv, Wo, Xb, Wqb, Wkb, Wvb, Wob);

    qkv_mix512<<<dim3(512), 512, 0, stream>>>(Xb, Wqb, Qb, Kb, Vtb);
    attn_kernel<<<dim3(1024), 256, 0, stream>>>(Qb, Kb, Vtb, Yb);
    proj_gemm8<<<dim3(256), 512, 0, stream>>>(Yb, Wob, bo, (float*)d_out);
}